// Round 12
// baseline (140.536 us; speedup 1.0000x reference)
//
#include <hip/hip_runtime.h>

#define NB 2048
#define CNT 32768.0f   // per-channel count = B*H*W = 2048*16

// workspace float offsets (activations are bf16/ushort)
#define OFF_Y1   0          // 2048*512 ush
#define OFF_Y2   524288     // 2048*1024 ush
#define OFF_Y3   1572864    // 2048*2048 ush
#define OFF_MEAN 3670016    // 2048*128 f pooled channel sums
#define OFF_ST   3932160    // 4 layers x 256 f
#define OFF_W2P  3933184    // 18432 ush
#define OFF_W3P  3942400    // 73728 ush
#define OFF_WPP  3979264    // 36864 ush
#define OFF_WDP  3997696    // 147456 ush

typedef __attribute__((ext_vector_type(8))) short bf16x8;
typedef __attribute__((ext_vector_type(4))) float f32x4;

__device__ __forceinline__ unsigned short f2bf(float f) {
  union { float f; unsigned int u; } v; v.f = f;
  unsigned int r = v.u + 0x7FFFu + ((v.u >> 16) & 1u);
  return (unsigned short)(r >> 16);
}
__device__ __forceinline__ float bf2f(unsigned short u) {
  union { unsigned int u; float f; } v; v.u = ((unsigned int)u) << 16;
  return v.f;
}

// pack conv weight [CO][CI][3][3] -> bf16 B-fragments, tap-major K (step = tap*KST+ks)
__device__ __forceinline__ void packw_one(const float* __restrict__ w, unsigned short* __restrict__ wpk,
                                          int CI, int CO, int NT, int i) {
  int KST = CI >> 5;
  int j = i & 7, l = (i >> 3) & 63, sn = i >> 9;
  int nt = sn % NT, step = sn / NT;
  int tap = step / KST, ks = step - tap * KST;
  int ci = ks * 32 + (l >> 4) * 8 + j, co = nt * 16 + (l & 15);
  wpk[i] = (co < CO) ? f2bf(w[(co * CI + ci) * 9 + tap]) : (unsigned short)0;
}

// pack Wd with K-order k = n*128 + ci  (n = tap index)
__device__ __forceinline__ void packwd_one(const float* __restrict__ Wd, unsigned short* __restrict__ wdp, int i) {
  int co = i / 1152, k = i % 1152;
  int n = k >> 7, ci = k & 127;
  int tt = k >> 5, kk = k & 31, g = kk >> 3, j = kk & 7;
  int nt = co >> 4, cc = co & 15, l = g * 16 + cc;
  wdp[((tt * 8 + nt) * 64 + l) * 8 + j] = f2bf(Wd[co * 1152 + ci * 9 + n]);
}

// merged: blocks [0,270) pack weights; blocks [270,782) conv1, 4 images each
__global__ __launch_bounds__(256) void k_pre(const float* __restrict__ W2, const float* __restrict__ W3,
                                             const float* __restrict__ Wp, const float* __restrict__ Wd,
                                             unsigned short* __restrict__ w2p, unsigned short* __restrict__ w3p,
                                             unsigned short* __restrict__ wpp, unsigned short* __restrict__ wdp,
                                             const float* __restrict__ x, const float* __restrict__ W1,
                                             unsigned short* __restrict__ y1, float* __restrict__ st) {
  __shared__ float xs[192];
  __shared__ float w1s[864];
  __shared__ float sst[64];
  int t = threadIdx.x;
  if (blockIdx.x < 270) {
#pragma unroll
    for (int ii = 0; ii < 4; ++ii) {
      int i = blockIdx.x * 1024 + ii * 256 + t;
      if (i < 18432) packw_one(W2, w2p, 32, 64, 4, i);
      else if (i < 92160) packw_one(W3, w3p, 64, 128, 8, i - 18432);
      else if (i < 129024) packw_one(Wp, wpp, 128, 18, 2, i - 92160);
      else if (i < 276480) packwd_one(Wd, wdp, i - 129024);
    }
    return;
  }
  int b0 = (blockIdx.x - 270) * 4;
  if (t < 192) xs[t] = x[b0 * 48 + t];
  for (int i = t; i < 864; i += 256) w1s[i] = W1[i];
  if (t < 64) sst[t] = 0.f;
  __syncthreads();
  for (int r = 0; r < 2; ++r) {
    int o = t + r * 256;
    int co = o >> 4, p = o & 15, h = p >> 2, w = p & 3;
    float s1 = 0.f, s2 = 0.f;
#pragma unroll
    for (int img = 0; img < 4; ++img) {
      float acc = 0.f;
      for (int ci = 0; ci < 3; ++ci) {
#pragma unroll
        for (int kx = 0; kx < 3; ++kx) {
          int ih = h + kx - 1;
          if (ih < 0 || ih > 3) continue;
#pragma unroll
          for (int ky = 0; ky < 3; ++ky) {
            int iw = w + ky - 1;
            if (iw < 0 || iw > 3) continue;
            acc += w1s[co * 27 + ci * 9 + kx * 3 + ky] * xs[img * 48 + ci * 16 + ih * 4 + iw];
          }
        }
      }
      acc = fmaxf(acc, 0.f);
      y1[(b0 + img) * 512 + o] = f2bf(acc);
      s1 += acc; s2 += acc * acc;
    }
    atomicAdd(&sst[co], s1);
    atomicAdd(&sst[32 + co], s2);
  }
  __syncthreads();
  if (t < 64) atomicAdd(&st[(t < 32) ? t : (96 + t)], sst[t]);
}

// MFMA conv 3x3 pad1 over 4x4; 4 images/block, 512 thr. (R11-proven)
template <int CI, int CO>
__global__ __launch_bounds__(512, 4) void k_convm(const unsigned short* __restrict__ yin,
                                                  const unsigned short* __restrict__ wpk,
                                                  const float* __restrict__ stp,
                                                  const float* __restrict__ gp,
                                                  const float* __restrict__ bpar,
                                                  unsigned short* __restrict__ yout, float* __restrict__ stout) {
  constexpr int KST = CI / 32, NSTEP = 9 * KST, NT = CO / 16;
  constexpr int STR = (CI == 64) ? 72 : 40;
  constexpr int IPW = (CO == 128) ? 4 : 2;
  __shared__ __align__(16) unsigned short xnT[4][36 * STR];
  __shared__ float cst[2][CO * 16];
  __shared__ float scS[2 * CI];
  __shared__ float sst[2 * CO];
  int b0 = blockIdx.x * 4, t = threadIdx.x;
  uint4 z = {0u, 0u, 0u, 0u};
  for (int i = t; i < (4 * 36 * STR) / 8; i += 512) ((uint4*)xnT)[i] = z;
  if (t < CI) {
    float m = stp[t] / CNT;
    float v = stp[128 + t] / CNT - m * m;
    float s = gp[t] * rsqrtf(fmaxf(v, 0.f) + 1e-5f);
    scS[t] = s; scS[CI + t] = bpar[t] - m * s;
  }
  if (t < 2 * CO) sst[t] = 0.f;
  __syncthreads();
  for (int i = t; i < 4 * CI * 16; i += 512) {
    int img = i / (CI * 16), r = i - img * (CI * 16);
    int c = r >> 4, p = r & 15, h = p >> 2, w = p & 3;
    float v = bf2f(yin[(b0 + img) * CI * 16 + r]) * scS[c] + scS[CI + c];
    xnT[img][((h + 1) * 6 + (w + 1)) * STR + c] = f2bf(v);
  }
  __syncthreads();
  int wv = t >> 6, l = t & 63, px = l & 15, g = l >> 4, cc = l & 15;
  int h = px >> 2, w = px & 3;
  int wq = (CO == 128) ? wv : (wv & 3);
  int ib = (CO == 128) ? 0 : ((wv >> 2) * 2);
  f32x4 acc[IPW];
#pragma unroll
  for (int e = 0; e < IPW; ++e) acc[e] = f32x4{0.f, 0.f, 0.f, 0.f};
#pragma unroll
  for (int step = 0; step < NSTEP; ++step) {
    int tap = step / KST, ks = step - tap * KST;
    int kx = tap / 3, ky = tap % 3;
    bf16x8 bb = *(const bf16x8*)&wpk[((step * NT + wq) * 64 + l) * 8];
    int woff = ((h + kx) * 6 + (w + ky)) * STR + ks * 32 + g * 8;
#pragma unroll
    for (int e = 0; e < IPW; ++e) {
      bf16x8 a = *(const bf16x8*)&xnT[ib + e][woff];
      acc[e] = __builtin_amdgcn_mfma_f32_16x16x32_bf16(a, bb, acc[e], 0, 0, 0);
    }
  }
  constexpr int EPT = CO / 16;
  constexpr int TPC = 256 / CO;
#pragma unroll
  for (int p = 0; p < 2; ++p) {
    if (CO == 128 || (wv >> 2) == p) {
#pragma unroll
      for (int e = 0; e < 2; ++e) {
        int src = (CO == 128) ? (2 * p + e) : e;
        int co = wq * 16 + cc;
#pragma unroll
        for (int r = 0; r < 4; ++r) cst[e][co * 16 + (g * 4 + r)] = acc[src][r];
      }
    }
    __syncthreads();
    {
      int ime = t >> 8, tl = t & 255;
      int c = tl / TPC, e0 = (tl % TPC) * EPT;
      float s1 = 0.f, s2 = 0.f;
      union { unsigned short u16[8]; uint4 u4; uint2 u2; } pk;
#pragma unroll
      for (int e = 0; e < EPT; ++e) {
        float v = fmaxf(cst[ime][c * 16 + e0 + e], 0.f);
        pk.u16[e] = f2bf(v);
        s1 += v; s2 += v * v;
      }
      unsigned short* dst = &yout[(b0 + 2 * p + ime) * CO * 16 + c * 16 + e0];
      if (EPT == 8) *(uint4*)dst = pk.u4; else *(uint2*)dst = pk.u2;
      atomicAdd(&sst[c], s1);
      atomicAdd(&sst[CO + c], s2);
    }
    __syncthreads();
  }
  if (t < 2 * CO) atomicAdd(&stout[(t < CO) ? t : (128 - CO + t)], sst[t]);
}

// deformable conv: 2 images/block; LDS 53760 B -> 3 blocks/CU; 4-phase xoffA.
// smem map: xnb2 [0,10240) 2x128x20; xnT [10240,29824) 2x36x136 / sAT overlay 2x9x16x36 [10240,30976);
// xoffA [30976,49408) 2x9x512 (cscr 8x256 f32 overlay); offs [49408,51712); scS; sst.
__global__ __launch_bounds__(512, 6) void k_deform(const unsigned short* __restrict__ y3,
                                                   const unsigned short* __restrict__ wppk,
                                                   const float* __restrict__ bp,
                                                   const unsigned short* __restrict__ wdp,
                                                   const float* __restrict__ stp,
                                                   const float* __restrict__ gp,
                                                   const float* __restrict__ bpar,
                                                   float* __restrict__ meanw, float* __restrict__ stout) {
  __shared__ __align__(16) unsigned char smem[53760];
  unsigned short* xnb2 = (unsigned short*)smem;
  unsigned short* xnT  = (unsigned short*)(smem + 10240);
  unsigned short* sAT  = (unsigned short*)(smem + 10240);
  unsigned short* xoffA = (unsigned short*)(smem + 30976);
  float* cscr = (float*)(smem + 30976);
  float* offs = (float*)(smem + 49408);
  float* scS  = (float*)(smem + 51712);
  float* sst  = (float*)(smem + 52736);
  int b0 = blockIdx.x * 2, t = threadIdx.x;
  uint4 z = {0u, 0u, 0u, 0u};
  for (int i = t; i < 1864; i += 512) ((uint4*)smem)[i] = z;  // zero xnb2 + xnT
  if (t < 128) {
    float m = stp[t] / CNT;
    float v = stp[128 + t] / CNT - m * m;
    float s = gp[t] * rsqrtf(fmaxf(v, 0.f) + 1e-5f);
    scS[t] = s; scS[128 + t] = bpar[t] - m * s;
  }
  if (t < 256) sst[t] = 0.f;
  __syncthreads();
  for (int i = t; i < 4096; i += 512) {
    int img = i >> 11, r = i & 2047;
    int c = r >> 4, p = r & 15, h = p >> 2, w = p & 3;
    float v = bf2f(y3[(b0 + img) * 2048 + r]) * scS[c] + scS[128 + c];
    unsigned short bv = f2bf(v);
    xnb2[img * 2560 + c * 20 + p] = bv;
    xnT[img * 4896 + ((h + 1) * 6 + (w + 1)) * 136 + c] = bv;
  }
  __syncthreads();
  int wv = t >> 6, l = t & 63, px = l & 15, g = l >> 4, cc = l & 15;
  int h = px >> 2, w = px & 3;
  // offset conv via MFMA: wave = (img, K-half, nt); 18 K-steps each
  {
    int imo = wv >> 2, half = (wv >> 1) & 1, nt = wv & 1;
    f32x4 oa = {0.f, 0.f, 0.f, 0.f};
#pragma unroll
    for (int si = 0; si < 18; ++si) {
      int s2 = half * 18 + si;
      int tap = s2 >> 2, ks = s2 & 3;
      int kx = tap / 3, ky = tap % 3;
      bf16x8 a = *(const bf16x8*)&xnT[imo * 4896 + ((h + kx) * 6 + (w + ky)) * 136 + ks * 32 + g * 8];
      bf16x8 bb = *(const bf16x8*)&wppk[((s2 * 2 + nt) * 64 + l) * 8];
      oa = __builtin_amdgcn_mfma_f32_16x16x32_bf16(a, bb, oa, 0, 0, 0);
    }
#pragma unroll
    for (int r = 0; r < 4; ++r) cscr[wv * 256 + (g * 4 + r) * 16 + px] = oa[r];
  }
  __syncthreads();
  // reduce partials -> offs[img]
  for (int i = t; i < 576; i += 512) {
    int imo = i / 288, r = i - imo * 288;
    int o = r >> 4, pp = r & 15;
    int nt = o >> 4, cc2 = o & 15;
    float v = bp[o] + cscr[(imo * 4 + nt) * 256 + pp * 16 + cc2]
            + cscr[(imo * 4 + 2 + nt) * 256 + pp * 16 + cc2];
    offs[imo * 288 + o * 16 + pp] = v;
  }
  __syncthreads();
  for (int i = t; i < 1296; i += 512) ((uint4*)(smem + 10240))[i] = z;  // zero sAT
  __syncthreads();
  // sampling -> scatter bilinear weights into S^T per image (stride 36)
  if (t < 288) {
    int imo = t / 144, r = t - imo * 144;
    int p = r / 9, n = r % 9;
    int hh = p >> 2, ww = p & 3;
    float sx = offs[imo * 288 + n * 16 + p] + (float)(hh + 1) + (float)(n / 3 - 1);
    float sy = offs[imo * 288 + (9 + n) * 16 + p] + (float)(ww + 1) + (float)(n % 3 - 1);
    float fx = floorf(sx), fy = floorf(sy);
    float qlx = fminf(fmaxf(fx, 0.f), 5.f);
    float qly = fminf(fmaxf(fy, 0.f), 5.f);
    float qrx = fminf(fmaxf(fx + 1.f, 0.f), 5.f);
    float qry = fminf(fmaxf(fy + 1.f, 0.f), 5.f);
    float pxc = fminf(fmaxf(sx, 0.f), 5.f);
    float pyc = fminf(fmaxf(sy, 0.f), 5.f);
    float glt = (1.f + (qlx - pxc)) * (1.f + (qly - pyc));
    float grb = (1.f - (qrx - pxc)) * (1.f - (qry - pyc));
    float glb = (1.f + (qlx - pxc)) * (1.f - (qry - pyc));
    float grt = (1.f - (qrx - pxc)) * (1.f + (qly - pyc));
    int ilx = (int)qlx, ily = (int)qly, irx = (int)qrx, iry = (int)qry;
    int rowb = imo * 5184 + (n * 16 + p) * 36;
    auto PUT = [&](int qx, int qy, float gv) {
      if (qx >= 1 && qx <= 4 && qy >= 1 && qy <= 4)
        sAT[rowb + (qx - 1) * 4 + (qy - 1)] = f2bf(gv);
    };
    PUT(ilx, ily, glt);
    PUT(irx, iry, grb);
    PUT(ilx, iry, glb);
    PUT(irx, ily, grt);
  }
  __syncthreads();
  // 4 phases x { build 2x9 K-steps of xoffA; barrier; consume 9 K-steps x 2 images }
  f32x4 acc0 = {0.f, 0.f, 0.f, 0.f};
  f32x4 acc1 = {0.f, 0.f, 0.f, 0.f};
  for (int ph = 0; ph < 4; ++ph) {
    for (int m = wv; m < 36; m += 8) {
      int imo = m / 18, mm = m - imo * 18;
      int ttl = mm >> 1;
      int tt = ph * 9 + ttl;
      int q = tt & 3, n = tt >> 2;
      int ct = 2 * q + (mm & 1);
      bf16x8 a = *(const bf16x8*)&xnb2[imo * 2560 + (ct * 16 + cc) * 20 + g * 8];
      bf16x8 bS = *(const bf16x8*)&sAT[imo * 5184 + (n * 16 + cc) * 36 + g * 8];
      f32x4 d = __builtin_amdgcn_mfma_f32_16x16x32_bf16(a, bS, f32x4{0.f, 0.f, 0.f, 0.f}, 0, 0, 0);
      int gp2 = (ct & 1) * 2 + (g >> 1);
      unsigned lo = (unsigned)f2bf(d[0]) | ((unsigned)f2bf(d[1]) << 16);
      unsigned hi = (unsigned)f2bf(d[2]) | ((unsigned)f2bf(d[3]) << 16);
      *(uint2*)&xoffA[imo * 4608 + (ttl * 64 + gp2 * 16 + cc) * 8 + (g & 1) * 4] = (uint2){lo, hi};
    }
    __syncthreads();
    __builtin_amdgcn_s_setprio(1);
#pragma unroll
    for (int ti = 0; ti < 9; ++ti) {
      bf16x8 bb = *(const bf16x8*)&wdp[(((ph * 9 + ti) * 8 + wv) * 64 + l) * 8];
      bf16x8 a0 = *(const bf16x8*)&xoffA[(ti * 64 + l) * 8];
      bf16x8 a1 = *(const bf16x8*)&xoffA[4608 + (ti * 64 + l) * 8];
      acc0 = __builtin_amdgcn_mfma_f32_16x16x32_bf16(a0, bb, acc0, 0, 0, 0);
      acc1 = __builtin_amdgcn_mfma_f32_16x16x32_bf16(a1, bb, acc1, 0, 0, 0);
    }
    __builtin_amdgcn_s_setprio(0);
    __syncthreads();
  }
  // epilogue: relu + in-register pooled sums + stats
  {
    float s1a = 0.f, s2a = 0.f, s1b = 0.f, s2b = 0.f;
#pragma unroll
    for (int r = 0; r < 4; ++r) {
      float v0 = fmaxf(acc0[r], 0.f);
      float v1 = fmaxf(acc1[r], 0.f);
      s1a += v0; s2a += v0 * v0;
      s1b += v1; s2b += v1 * v1;
    }
    s1a += __shfl_xor(s1a, 16); s1a += __shfl_xor(s1a, 32);
    s2a += __shfl_xor(s2a, 16); s2a += __shfl_xor(s2a, 32);
    s1b += __shfl_xor(s1b, 16); s1b += __shfl_xor(s1b, 32);
    s2b += __shfl_xor(s2b, 16); s2b += __shfl_xor(s2b, 32);
    if (g == 0) {
      int co = wv * 16 + cc;
      meanw[b0 * 128 + co] = s1a;
      meanw[(b0 + 1) * 128 + co] = s1b;
      atomicAdd(&sst[co], s1a + s1b);
      atomicAdd(&sst[128 + co], s2a + s2b);
    }
  }
  __syncthreads();
  if (t < 256) atomicAdd(&stout[t], sst[t]);
}

// final: BN4 fold + linear on pooled sums. 80 blocks x 256 thr, thread = (img, o).
__global__ __launch_bounds__(256) void k_final(const float* __restrict__ mean,
                                               const float* __restrict__ stp,
                                               const float* __restrict__ gp,
                                               const float* __restrict__ bpar,
                                               const float* __restrict__ Wc, const float* __restrict__ bc,
                                               float* __restrict__ out) {
  __shared__ float wf[1280];
  __shared__ float scS[256];
  __shared__ float tb[10];
  int t = threadIdx.x;
  if (t < 128) {
    float m = stp[t] / CNT;
    float v = stp[128 + t] / CNT - m * m;
    float s = gp[t] * rsqrtf(fmaxf(v, 0.f) + 1e-5f);
    scS[t] = s; scS[128 + t] = bpar[t] - m * s;
  }
  __syncthreads();
  for (int i = t; i < 1280; i += 256) {
    int c = i & 127;
    wf[i] = Wc[i] * scS[c] * 0.0625f;
  }
  __syncthreads();
  if (t < 10) {
    float s = bc[t];
    for (int c = 0; c < 128; ++c) s += Wc[t * 128 + c] * scS[128 + c];
    tb[t] = s;
  }
  __syncthreads();
  int gidx = blockIdx.x * 256 + t;
  int img = gidx / 10, o = gidx - img * 10;
  const float* mr = mean + img * 128;
  const float* wr = wf + o * 128;
  float acc = tb[o];
#pragma unroll 8
  for (int c = 0; c < 128; ++c) acc += wr[c] * mr[c];
  out[gidx] = acc;
}

extern "C" void kernel_launch(void* const* d_in, const int* in_sizes, int n_in,
                              void* d_out, int out_size, void* d_ws, size_t ws_size,
                              hipStream_t stream) {
  const float* x  = (const float*)d_in[0];
  const float* W1 = (const float*)d_in[1];
  const float* g1 = (const float*)d_in[2];
  const float* b1 = (const float*)d_in[3];
  const float* W2 = (const float*)d_in[4];
  const float* g2 = (const float*)d_in[5];
  const float* b2 = (const float*)d_in[6];
  const float* W3 = (const float*)d_in[7];
  const float* g3 = (const float*)d_in[8];
  const float* b3 = (const float*)d_in[9];
  const float* Wp = (const float*)d_in[10];
  const float* bp = (const float*)d_in[11];
  const float* Wd = (const float*)d_in[12];
  const float* g4 = (const float*)d_in[13];
  const float* b4 = (const float*)d_in[14];
  const float* Wc = (const float*)d_in[15];
  const float* bc = (const float*)d_in[16];
  float* ws = (float*)d_ws;
  float* out = (float*)d_out;

  hipMemsetAsync(ws + OFF_ST, 0, 1024 * sizeof(float), stream);
  k_pre<<<782, 256, 0, stream>>>(W2, W3, Wp, Wd,
                                 (unsigned short*)(ws + OFF_W2P), (unsigned short*)(ws + OFF_W3P),
                                 (unsigned short*)(ws + OFF_WPP), (unsigned short*)(ws + OFF_WDP),
                                 x, W1, (unsigned short*)(ws + OFF_Y1), ws + OFF_ST);
  k_convm<32, 64><<<NB / 4, 512, 0, stream>>>((const unsigned short*)(ws + OFF_Y1),
                                              (const unsigned short*)(ws + OFF_W2P),
                                              ws + OFF_ST, g1, b1,
                                              (unsigned short*)(ws + OFF_Y2), ws + OFF_ST + 256);
  k_convm<64, 128><<<NB / 4, 512, 0, stream>>>((const unsigned short*)(ws + OFF_Y2),
                                               (const unsigned short*)(ws + OFF_W3P),
                                               ws + OFF_ST + 256, g2, b2,
                                               (unsigned short*)(ws + OFF_Y3), ws + OFF_ST + 512);
  k_deform<<<NB / 2, 512, 0, stream>>>((const unsigned short*)(ws + OFF_Y3),
                                       (const unsigned short*)(ws + OFF_WPP), bp,
                                       (const unsigned short*)(ws + OFF_WDP),
                                       ws + OFF_ST + 512, g3, b3, ws + OFF_MEAN, ws + OFF_ST + 768);
  k_final<<<80, 256, 0, stream>>>(ws + OFF_MEAN, ws + OFF_ST + 768, g4, b4, Wc, bc, out);
}

// Round 13
// 117.605 us; speedup vs baseline: 1.1950x; 1.1950x over previous
//
#include <hip/hip_runtime.h>

#define NB 2048
#define CNT 32768.0f   // per-channel count = B*H*W = 2048*16

// workspace float offsets (activations are bf16/ushort)
#define OFF_Y1   0          // 2048*512 ush
#define OFF_Y2   524288     // 2048*1024 ush
#define OFF_Y3   1572864    // 2048*2048 ush
#define OFF_MEAN 3670016    // 2048*128 f pooled channel sums
#define OFF_ST   3932160    // 4 layers x 256 f
#define OFF_W2P  3933184    // 18432 ush
#define OFF_W3P  3942400    // 73728 ush
#define OFF_WPP  3979264    // 36864 ush
#define OFF_WDP  3997696    // 147456 ush

typedef __attribute__((ext_vector_type(8))) short bf16x8;
typedef __attribute__((ext_vector_type(4))) float f32x4;

__device__ __forceinline__ unsigned short f2bf(float f) {
  union { float f; unsigned int u; } v; v.f = f;
  unsigned int r = v.u + 0x7FFFu + ((v.u >> 16) & 1u);
  return (unsigned short)(r >> 16);
}
__device__ __forceinline__ float bf2f(unsigned short u) {
  union { unsigned int u; float f; } v; v.u = ((unsigned int)u) << 16;
  return v.f;
}

// pack conv weight [CO][CI][3][3] -> bf16 B-fragments, tap-major K (step = tap*KST+ks)
__device__ __forceinline__ void packw_one(const float* __restrict__ w, unsigned short* __restrict__ wpk,
                                          int CI, int CO, int NT, int i) {
  int KST = CI >> 5;
  int j = i & 7, l = (i >> 3) & 63, sn = i >> 9;
  int nt = sn % NT, step = sn / NT;
  int tap = step / KST, ks = step - tap * KST;
  int ci = ks * 32 + (l >> 4) * 8 + j, co = nt * 16 + (l & 15);
  wpk[i] = (co < CO) ? f2bf(w[(co * CI + ci) * 9 + tap]) : (unsigned short)0;
}

// pack Wd with K-order k = n*128 + ci  (n = tap index)
__device__ __forceinline__ void packwd_one(const float* __restrict__ Wd, unsigned short* __restrict__ wdp, int i) {
  int co = i / 1152, k = i % 1152;
  int tt = k >> 5, kk = k & 31, g = kk >> 3, j = kk & 7;
  int n = k >> 7, ci = k & 127;
  int nt = co >> 4, cc = co & 15, l = g * 16 + cc;
  wdp[((tt * 8 + nt) * 64 + l) * 8 + j] = f2bf(Wd[co * 1152 + ci * 9 + n]);
}

// merged: blocks [0,270) pack weights; blocks [270,782) conv1, 4 images each
__global__ __launch_bounds__(256) void k_pre(const float* __restrict__ W2, const float* __restrict__ W3,
                                             const float* __restrict__ Wp, const float* __restrict__ Wd,
                                             unsigned short* __restrict__ w2p, unsigned short* __restrict__ w3p,
                                             unsigned short* __restrict__ wpp, unsigned short* __restrict__ wdp,
                                             const float* __restrict__ x, const float* __restrict__ W1,
                                             unsigned short* __restrict__ y1, float* __restrict__ st) {
  __shared__ float xs[192];
  __shared__ float w1s[864];
  __shared__ float sst[64];
  int t = threadIdx.x;
  if (blockIdx.x < 270) {
#pragma unroll
    for (int ii = 0; ii < 4; ++ii) {
      int i = blockIdx.x * 1024 + ii * 256 + t;
      if (i < 18432) packw_one(W2, w2p, 32, 64, 4, i);
      else if (i < 92160) packw_one(W3, w3p, 64, 128, 8, i - 18432);
      else if (i < 129024) packw_one(Wp, wpp, 128, 18, 2, i - 92160);
      else if (i < 276480) packwd_one(Wd, wdp, i - 129024);
    }
    return;
  }
  int b0 = (blockIdx.x - 270) * 4;
  if (t < 192) xs[t] = x[b0 * 48 + t];
  for (int i = t; i < 864; i += 256) w1s[i] = W1[i];
  if (t < 64) sst[t] = 0.f;
  __syncthreads();
  for (int r = 0; r < 2; ++r) {
    int o = t + r * 256;
    int co = o >> 4, p = o & 15, h = p >> 2, w = p & 3;
    float s1 = 0.f, s2 = 0.f;
#pragma unroll
    for (int img = 0; img < 4; ++img) {
      float acc = 0.f;
      for (int ci = 0; ci < 3; ++ci) {
#pragma unroll
        for (int kx = 0; kx < 3; ++kx) {
          int ih = h + kx - 1;
          if (ih < 0 || ih > 3) continue;
#pragma unroll
          for (int ky = 0; ky < 3; ++ky) {
            int iw = w + ky - 1;
            if (iw < 0 || iw > 3) continue;
            acc += w1s[co * 27 + ci * 9 + kx * 3 + ky] * xs[img * 48 + ci * 16 + ih * 4 + iw];
          }
        }
      }
      acc = fmaxf(acc, 0.f);
      y1[(b0 + img) * 512 + o] = f2bf(acc);
      s1 += acc; s2 += acc * acc;
    }
    atomicAdd(&sst[co], s1);
    atomicAdd(&sst[32 + co], s2);
  }
  __syncthreads();
  if (t < 64) atomicAdd(&st[(t < 32) ? t : (96 + t)], sst[t]);
}

// MFMA conv 3x3 pad1 over 4x4; NIMG images/block, 512 thr, 4 acc chains per B-load.
// conv2: NIMG=8, wave = (img-quad, N-tile); conv3: NIMG=4, wave = N-tile (all 4 images).
template <int CI, int CO, int NIMG>
__global__ __launch_bounds__(512, 4) void k_convm(const unsigned short* __restrict__ yin,
                                                  const unsigned short* __restrict__ wpk,
                                                  const float* __restrict__ stp,
                                                  const float* __restrict__ gp,
                                                  const float* __restrict__ bpar,
                                                  unsigned short* __restrict__ yout, float* __restrict__ stout) {
  constexpr int KST = CI / 32, NSTEP = 9 * KST, NT = CO / 16;
  constexpr int STR = (CI == 64) ? 72 : 40;
  constexpr int CPASS = NIMG / 2;      // images per epilogue pass (2 passes)
  __shared__ __align__(16) unsigned short xnT[NIMG][36 * STR];
  __shared__ float cst[CPASS][CO * 16];
  __shared__ float scS[2 * CI];
  __shared__ float sst[2 * CO];
  int b0 = blockIdx.x * NIMG, t = threadIdx.x;
  uint4 z = {0u, 0u, 0u, 0u};
  for (int i = t; i < (NIMG * 36 * STR) / 8; i += 512) ((uint4*)xnT)[i] = z;
  if (t < CI) {
    float m = stp[t] / CNT;
    float v = stp[128 + t] / CNT - m * m;
    float s = gp[t] * rsqrtf(fmaxf(v, 0.f) + 1e-5f);
    scS[t] = s; scS[CI + t] = bpar[t] - m * s;
  }
  if (t < 2 * CO) sst[t] = 0.f;
  __syncthreads();
  for (int i = t; i < NIMG * CI * 16; i += 512) {
    int img = i / (CI * 16), r = i - img * (CI * 16);
    int c = r >> 4, p = r & 15, h = p >> 2, w = p & 3;
    float v = bf2f(yin[(b0 + img) * CI * 16 + r]) * scS[c] + scS[CI + c];
    xnT[img][((h + 1) * 6 + (w + 1)) * STR + c] = f2bf(v);
  }
  __syncthreads();
  int wv = t >> 6, l = t & 63, px = l & 15, g = l >> 4, cc = l & 15;
  int h = px >> 2, w = px & 3;
  int wq = (NT == 8) ? wv : (wv & 3);
  int ib = (NT == 8) ? 0 : ((wv >> 2) * 4);   // base image of this wave's 4 chains
  f32x4 acc[4];
#pragma unroll
  for (int e = 0; e < 4; ++e) acc[e] = f32x4{0.f, 0.f, 0.f, 0.f};
#pragma unroll
  for (int step = 0; step < NSTEP; ++step) {
    int tap = step / KST, ks = step - tap * KST;
    int kx = tap / 3, ky = tap % 3;
    bf16x8 bb = *(const bf16x8*)&wpk[((step * NT + wq) * 64 + l) * 8];
    int woff = ((h + kx) * 6 + (w + ky)) * STR + ks * 32 + g * 8;
#pragma unroll
    for (int e = 0; e < 4; ++e) {
      bf16x8 a = *(const bf16x8*)&xnT[ib + e][woff];
      acc[e] = __builtin_amdgcn_mfma_f32_16x16x32_bf16(a, bb, acc[e], 0, 0, 0);
    }
  }
  // epilogue: 2 passes of CPASS images through cst
#pragma unroll
  for (int p = 0; p < 2; ++p) {
    if (NT == 8) {
      // conv3: every wave holds images 0..3; pass p covers images 2p, 2p+1
#pragma unroll
      for (int e = 0; e < 2; ++e) {
        int co = wq * 16 + cc;
#pragma unroll
        for (int r = 0; r < 4; ++r) cst[e][co * 16 + (g * 4 + r)] = acc[2 * p + e][r];
      }
    } else {
      // conv2: waves with img-quad == p write their 4 images
      if ((wv >> 2) == p) {
#pragma unroll
        for (int e = 0; e < 4; ++e) {
          int co = wq * 16 + cc;
#pragma unroll
          for (int r = 0; r < 4; ++r) cst[e][co * 16 + (g * 4 + r)] = acc[e][r];
        }
      }
    }
    __syncthreads();
    {
      // 8 values/thread in both configs (CPASS*CO*16 == 4096)
      int ime, c;
      if (NT == 8) { ime = t >> 8; int tl = t & 255; c = tl >> 1; }
      else         { ime = t >> 7; int tl = t & 127; c = tl >> 1; }
      int e0 = (t & 1) * 8;
      float s1 = 0.f, s2 = 0.f;
      union { unsigned short u16[8]; uint4 u4; } pk;
#pragma unroll
      for (int e = 0; e < 8; ++e) {
        float v = fmaxf(cst[ime][c * 16 + e0 + e], 0.f);
        pk.u16[e] = f2bf(v);
        s1 += v; s2 += v * v;
      }
      *(uint4*)&yout[(b0 + CPASS * p + ime) * CO * 16 + c * 16 + e0] = pk.u4;
      atomicAdd(&sst[c], s1);
      atomicAdd(&sst[CO + c], s2);
    }
    __syncthreads();
  }
  if (t < 2 * CO) atomicAdd(&stout[(t < CO) ? t : (128 - CO + t)], sst[t]);
}

// deformable conv: R11-proven config — 2 images/block, 2-phase, LDS 76544, launch_bounds(512,4).
__global__ __launch_bounds__(512, 4) void k_deform(const unsigned short* __restrict__ y3,
                                                   const unsigned short* __restrict__ wppk,
                                                   const float* __restrict__ bp,
                                                   const unsigned short* __restrict__ wdp,
                                                   const float* __restrict__ stp,
                                                   const float* __restrict__ gp,
                                                   const float* __restrict__ bpar,
                                                   float* __restrict__ meanw, float* __restrict__ stout) {
  __shared__ __align__(16) unsigned char smem[76544];
  unsigned short* xnb2 = (unsigned short*)smem;             // [0,12288) 2 x 128x24
  unsigned short* xnT  = (unsigned short*)(smem + 12288);   // [12288,31872) 2 x 36x136
  unsigned short* sAT  = (unsigned short*)(smem + 12288);   // overlay: 2 x 9x16x40
  float* cscr = (float*)(smem + 35328);                     // overlay: 8x256 partials
  unsigned short* xoffA = (unsigned short*)(smem + 35328);  // 2 x 18x512 per phase
  float* offs = (float*)(smem + 72192);                     // 2 x 288
  float* scS  = (float*)(smem + 74496);                     // 256
  float* sst  = (float*)(smem + 75520);                     // 256
  int b0 = blockIdx.x * 2, t = threadIdx.x;
  uint4 z = {0u, 0u, 0u, 0u};
  for (int i = t; i < 1992; i += 512) ((uint4*)smem)[i] = z;
  if (t < 128) {
    float m = stp[t] / CNT;
    float v = stp[128 + t] / CNT - m * m;
    float s = gp[t] * rsqrtf(fmaxf(v, 0.f) + 1e-5f);
    scS[t] = s; scS[128 + t] = bpar[t] - m * s;
  }
  if (t < 256) sst[t] = 0.f;
  __syncthreads();
  for (int i = t; i < 4096; i += 512) {
    int img = i >> 11, r = i & 2047;
    int c = r >> 4, p = r & 15, h = p >> 2, w = p & 3;
    float v = bf2f(y3[(b0 + img) * 2048 + r]) * scS[c] + scS[128 + c];
    unsigned short bv = f2bf(v);
    xnb2[img * 3072 + c * 24 + p] = bv;
    xnT[img * 4896 + ((h + 1) * 6 + (w + 1)) * 136 + c] = bv;
  }
  __syncthreads();
  int wv = t >> 6, l = t & 63, px = l & 15, g = l >> 4, cc = l & 15;
  int h = px >> 2, w = px & 3;
  {
    int imo = wv >> 2, half = (wv >> 1) & 1, nt = wv & 1;
    f32x4 oa = {0.f, 0.f, 0.f, 0.f};
#pragma unroll
    for (int si = 0; si < 18; ++si) {
      int s2 = half * 18 + si;
      int tap = s2 >> 2, ks = s2 & 3;
      int kx = tap / 3, ky = tap % 3;
      bf16x8 a = *(const bf16x8*)&xnT[imo * 4896 + ((h + kx) * 6 + (w + ky)) * 136 + ks * 32 + g * 8];
      bf16x8 bb = *(const bf16x8*)&wppk[((s2 * 2 + nt) * 64 + l) * 8];
      oa = __builtin_amdgcn_mfma_f32_16x16x32_bf16(a, bb, oa, 0, 0, 0);
    }
#pragma unroll
    for (int r = 0; r < 4; ++r) cscr[wv * 256 + (g * 4 + r) * 16 + px] = oa[r];
  }
  __syncthreads();
  for (int i = t; i < 576; i += 512) {
    int imo = i / 288, r = i - imo * 288;
    int o = r >> 4, pp = r & 15;
    int nt = o >> 4, cc2 = o & 15;
    float v = bp[o] + cscr[(imo * 4 + nt) * 256 + pp * 16 + cc2]
            + cscr[(imo * 4 + 2 + nt) * 256 + pp * 16 + cc2];
    offs[imo * 288 + o * 16 + pp] = v;
  }
  __syncthreads();
  for (int i = t; i < 1440; i += 512) ((uint4*)(smem + 12288))[i] = z;
  __syncthreads();
  if (t < 288) {
    int imo = t / 144, r = t - imo * 144;
    int p = r / 9, n = r % 9;
    int hh = p >> 2, ww = p & 3;
    float sx = offs[imo * 288 + n * 16 + p] + (float)(hh + 1) + (float)(n / 3 - 1);
    float sy = offs[imo * 288 + (9 + n) * 16 + p] + (float)(ww + 1) + (float)(n % 3 - 1);
    float fx = floorf(sx), fy = floorf(sy);
    float qlx = fminf(fmaxf(fx, 0.f), 5.f);
    float qly = fminf(fmaxf(fy, 0.f), 5.f);
    float qrx = fminf(fmaxf(fx + 1.f, 0.f), 5.f);
    float qry = fminf(fmaxf(fy + 1.f, 0.f), 5.f);
    float pxc = fminf(fmaxf(sx, 0.f), 5.f);
    float pyc = fminf(fmaxf(sy, 0.f), 5.f);
    float glt = (1.f + (qlx - pxc)) * (1.f + (qly - pyc));
    float grb = (1.f - (qrx - pxc)) * (1.f - (qry - pyc));
    float glb = (1.f + (qlx - pxc)) * (1.f - (qry - pyc));
    float grt = (1.f - (qrx - pxc)) * (1.f + (qly - pyc));
    int ilx = (int)qlx, ily = (int)qly, irx = (int)qrx, iry = (int)qry;
    int rowb = imo * 5760 + (n * 16 + p) * 40;
    auto PUT = [&](int qx, int qy, float gv) {
      if (qx >= 1 && qx <= 4 && qy >= 1 && qy <= 4)
        sAT[rowb + (qx - 1) * 4 + (qy - 1)] = f2bf(gv);
    };
    PUT(ilx, ily, glt);
    PUT(irx, iry, grb);
    PUT(ilx, iry, glb);
    PUT(irx, ily, grt);
  }
  __syncthreads();
  f32x4 acc0 = {0.f, 0.f, 0.f, 0.f};
  f32x4 acc1 = {0.f, 0.f, 0.f, 0.f};
  for (int ph = 0; ph < 2; ++ph) {
    for (int m = wv; m < 72; m += 8) {
      int imo = m / 36, mm = m - imo * 36;
      int ttl = mm >> 1;
      int tt = ph * 18 + ttl;
      int q = tt & 3, n = tt >> 2;
      int ct = 2 * q + (mm & 1);
      bf16x8 a = *(const bf16x8*)&xnb2[imo * 3072 + (ct * 16 + cc) * 24 + g * 8];
      bf16x8 bS = *(const bf16x8*)&sAT[imo * 5760 + (n * 16 + cc) * 40 + g * 8];
      f32x4 d = __builtin_amdgcn_mfma_f32_16x16x32_bf16(a, bS, f32x4{0.f, 0.f, 0.f, 0.f}, 0, 0, 0);
      int gp2 = (ct & 1) * 2 + (g >> 1);
      unsigned lo = (unsigned)f2bf(d[0]) | ((unsigned)f2bf(d[1]) << 16);
      unsigned hi = (unsigned)f2bf(d[2]) | ((unsigned)f2bf(d[3]) << 16);
      *(uint2*)&xoffA[imo * 9216 + (ttl * 64 + gp2 * 16 + cc) * 8 + (g & 1) * 4] = (uint2){lo, hi};
    }
    __syncthreads();
#pragma unroll
    for (int ti = 0; ti < 18; ++ti) {
      bf16x8 bb = *(const bf16x8*)&wdp[(((ph * 18 + ti) * 8 + wv) * 64 + l) * 8];
      bf16x8 a0 = *(const bf16x8*)&xoffA[(ti * 64 + l) * 8];
      bf16x8 a1 = *(const bf16x8*)&xoffA[9216 + (ti * 64 + l) * 8];
      acc0 = __builtin_amdgcn_mfma_f32_16x16x32_bf16(a0, bb, acc0, 0, 0, 0);
      acc1 = __builtin_amdgcn_mfma_f32_16x16x32_bf16(a1, bb, acc1, 0, 0, 0);
    }
    __syncthreads();
  }
  {
    float s1a = 0.f, s2a = 0.f, s1b = 0.f, s2b = 0.f;
#pragma unroll
    for (int r = 0; r < 4; ++r) {
      float v0 = fmaxf(acc0[r], 0.f);
      float v1 = fmaxf(acc1[r], 0.f);
      s1a += v0; s2a += v0 * v0;
      s1b += v1; s2b += v1 * v1;
    }
    s1a += __shfl_xor(s1a, 16); s1a += __shfl_xor(s1a, 32);
    s2a += __shfl_xor(s2a, 16); s2a += __shfl_xor(s2a, 32);
    s1b += __shfl_xor(s1b, 16); s1b += __shfl_xor(s1b, 32);
    s2b += __shfl_xor(s2b, 16); s2b += __shfl_xor(s2b, 32);
    if (g == 0) {
      int co = wv * 16 + cc;
      meanw[b0 * 128 + co] = s1a;
      meanw[(b0 + 1) * 128 + co] = s1b;
      atomicAdd(&sst[co], s1a + s1b);
      atomicAdd(&sst[128 + co], s2a + s2b);
    }
  }
  __syncthreads();
  if (t < 256) atomicAdd(&stout[t], sst[t]);
}

// final: BN4 fold + linear on pooled sums. 80 blocks x 256 thr, thread = (img, o).
__global__ __launch_bounds__(256) void k_final(const float* __restrict__ mean,
                                               const float* __restrict__ stp,
                                               const float* __restrict__ gp,
                                               const float* __restrict__ bpar,
                                               const float* __restrict__ Wc, const float* __restrict__ bc,
                                               float* __restrict__ out) {
  __shared__ float wf[1280];
  __shared__ float scS[256];
  __shared__ float tb[10];
  int t = threadIdx.x;
  if (t < 128) {
    float m = stp[t] / CNT;
    float v = stp[128 + t] / CNT - m * m;
    float s = gp[t] * rsqrtf(fmaxf(v, 0.f) + 1e-5f);
    scS[t] = s; scS[128 + t] = bpar[t] - m * s;
  }
  __syncthreads();
  for (int i = t; i < 1280; i += 256) {
    int c = i & 127;
    wf[i] = Wc[i] * scS[c] * 0.0625f;
  }
  __syncthreads();
  if (t < 10) {
    float s = bc[t];
    for (int c = 0; c < 128; ++c) s += Wc[t * 128 + c] * scS[128 + c];
    tb[t] = s;
  }
  __syncthreads();
  int gidx = blockIdx.x * 256 + t;
  int img = gidx / 10, o = gidx - img * 10;
  const float* mr = mean + img * 128;
  const float* wr = wf + o * 128;
  float acc = tb[o];
#pragma unroll 8
  for (int c = 0; c < 128; ++c) acc += wr[c] * mr[c];
  out[gidx] = acc;
}

extern "C" void kernel_launch(void* const* d_in, const int* in_sizes, int n_in,
                              void* d_out, int out_size, void* d_ws, size_t ws_size,
                              hipStream_t stream) {
  const float* x  = (const float*)d_in[0];
  const float* W1 = (const float*)d_in[1];
  const float* g1 = (const float*)d_in[2];
  const float* b1 = (const float*)d_in[3];
  const float* W2 = (const float*)d_in[4];
  const float* g2 = (const float*)d_in[5];
  const float* b2 = (const float*)d_in[6];
  const float* W3 = (const float*)d_in[7];
  const float* g3 = (const float*)d_in[8];
  const float* b3 = (const float*)d_in[9];
  const float* Wp = (const float*)d_in[10];
  const float* bp = (const float*)d_in[11];
  const float* Wd = (const float*)d_in[12];
  const float* g4 = (const float*)d_in[13];
  const float* b4 = (const float*)d_in[14];
  const float* Wc = (const float*)d_in[15];
  const float* bc = (const float*)d_in[16];
  float* ws = (float*)d_ws;
  float* out = (float*)d_out;

  hipMemsetAsync(ws + OFF_ST, 0, 1024 * sizeof(float), stream);
  k_pre<<<782, 256, 0, stream>>>(W2, W3, Wp, Wd,
                                 (unsigned short*)(ws + OFF_W2P), (unsigned short*)(ws + OFF_W3P),
                                 (unsigned short*)(ws + OFF_WPP), (unsigned short*)(ws + OFF_WDP),
                                 x, W1, (unsigned short*)(ws + OFF_Y1), ws + OFF_ST);
  k_convm<32, 64, 8><<<NB / 8, 512, 0, stream>>>((const unsigned short*)(ws + OFF_Y1),
                                                 (const unsigned short*)(ws + OFF_W2P),
                                                 ws + OFF_ST, g1, b1,
                                                 (unsigned short*)(ws + OFF_Y2), ws + OFF_ST + 256);
  k_convm<64, 128, 4><<<NB / 4, 512, 0, stream>>>((const unsigned short*)(ws + OFF_Y2),
                                                  (const unsigned short*)(ws + OFF_W3P),
                                                  ws + OFF_ST + 256, g2, b2,
                                                  (unsigned short*)(ws + OFF_Y3), ws + OFF_ST + 512);
  k_deform<<<NB / 2, 512, 0, stream>>>((const unsigned short*)(ws + OFF_Y3),
                                       (const unsigned short*)(ws + OFF_WPP), bp,
                                       (const unsigned short*)(ws + OFF_WDP),
                                       ws + OFF_ST + 512, g3, b3, ws + OFF_MEAN, ws + OFF_ST + 768);
  k_final<<<80, 256, 0, stream>>>(ws + OFF_MEAN, ws + OFF_ST + 768, g4, b4, Wc, bc, out);
}